// Round 6
// baseline (2503.754 us; speedup 1.0000x reference)
//
#include <hip/hip_runtime.h>

typedef unsigned short u16;
typedef unsigned int u32;
typedef __attribute__((ext_vector_type(8))) __bf16 bf16x8;
typedef __attribute__((ext_vector_type(4))) float f32x4;

#define E_TILE 64
#define KP 160      // padded K: 128 h + 1 bias-one + 31 zeros
#define KL 168      // h LDS row stride in u16
#define EAS 40      // ea LDS row stride in u16
#define WNTOT 2304
#define NTILES 144  // 2304 / 16
#define CSF 68      // f32 coef stride
#define TPS 73      // tp scratch stride in f32

#define A0C   0.14433756729740643f   /* sqrt(1/48) */
#define A0IS3 0.08333333333333333f   /* A0/sqrt(3) = 1/12 */
#define A1IS3 0.14433756729740643f   /* (1/4)/sqrt(3) */

__device__ inline u16 f2bf(float f) {
    union { float f; u32 u; } v; v.f = f;
    u32 u = v.u;
    return (u16)((u + 0x7FFFu + ((u >> 16) & 1u)) >> 16);  // RNE
}

// w2frag: fragment-ordered W2T. idx = ((nt*5 + kk)*64 + lane)*8 + j
//   n = nt*16 + (lane&15); k = kk*32 + (lane>>4)*8 + j
//   value = k<128 ? W2[k][n] : (k==128 ? b2[n] : 0)
// w1t[n][k] = W1[k][n]
__global__ void prep_w(const float* __restrict__ w2, const float* __restrict__ b2,
                       const float* __restrict__ w1,
                       u16* __restrict__ w2frag, u16* __restrict__ w1t) {
    int idx = blockIdx.x * 256 + threadIdx.x;
    const int tot2 = NTILES * 5 * 64 * 8;   // 460800
    if (idx < tot2) {
        int j = idx & 7;
        int l = (idx >> 3) & 63;
        int f = idx >> 9;
        int nt = f / 5, kk = f - nt * 5;
        int n = nt * 16 + (l & 15);
        int k = kk * 32 + (l >> 4) * 8 + j;
        float v = 0.f;
        if (k < 128) v = w2[(size_t)k * WNTOT + n];
        else if (k == 128) v = b2[n];
        w2frag[idx] = f2bf(v);
    } else {
        int j = idx - tot2;
        if (j < 128 * 32) {
            int n = j >> 5, k = j & 31;
            w1t[j] = f2bf(w1[k * 128 + n]);
        }
    }
}

__global__ void count_k(const int* __restrict__ src, int E, int* __restrict__ cnt) {
    int i = blockIdx.x * 256 + threadIdx.x;
    if (i < E) atomicAdd(&cnt[src[i]], 1);
}

// single block, 1024 threads: cur = exclusive-prefix-sum(cnt)
__global__ void scan_k(const int* __restrict__ cnt, int* __restrict__ cur, int N) {
    __shared__ int part[1024];
    int t = threadIdx.x;
    int S = (N + 1023) >> 10;
    int lo = t * S; if (lo > N) lo = N;
    int hi = lo + S; if (hi > N) hi = N;
    int s = 0;
    for (int i = lo; i < hi; ++i) s += cnt[i];
    part[t] = s;
    __syncthreads();
    for (int d = 1; d < 1024; d <<= 1) {
        int add = (t >= d) ? part[t - d] : 0;
        __syncthreads();
        part[t] += add;
        __syncthreads();
    }
    int run = part[t] - s;   // exclusive
    for (int i = lo; i < hi; ++i) { cur[i] = run; run += cnt[i]; }
}

__global__ void scatter_k(const int* __restrict__ ei, int E,
                          int* __restrict__ cur, int* __restrict__ perm) {
    int e = blockIdx.x * 256 + threadIdx.x;
    if (e < E) {
        int s = ei[e];
        int p = atomicAdd(&cur[s], 1);
        perm[p] = e;
    }
}

__global__ void finalize_k(float* __restrict__ out, const int* __restrict__ cnt, int total) {
    int i = blockIdx.x * 256 + threadIdx.x;
    if (i >= total) return;
    float c = (float)cnt[i / 80];
    out[i] /= fmaxf(c, 1.0f);
}

__global__ __launch_bounds__(256, 4)
void tpcl_main(const float* __restrict__ node_attr,
               const int* __restrict__ edge_index,
               const float* __restrict__ edge_attr,
               const float* __restrict__ edge_sh,
               const u16* __restrict__ w1t,
               const float* __restrict__ fc_b1,
               const u16* __restrict__ w2frag,
               const int* __restrict__ perm,
               float* __restrict__ out,
               int N, int E)
{
    // Phase-unioned region (34816 B = max of the three):
    //   phase 0/1 : ea [64][EAS] u16 (5120 B) + h [64][KL] u16 at u16-ofs 2560 (21504 B)
    //   phase 1b/2: coef f32 [128][CSF] (34816 B)  rows: 0..31 L1, 32..63 X0, 64..111 X1, 112..127 L4
    //   phase 3   : tp f32 [80][TPS] (23360 B)
    alignas(16) __shared__ u16 uregion[17408];
    __shared__ float SHs[E_TILE][4];   // RAW sh0, s1a, s1b, s1c
    __shared__ int SRCs[E_TILE];
    __shared__ int RLEN[E_TILE];

    const int tid = threadIdx.x;
    const int ebase = blockIdx.x * E_TILE;
    const int lane = tid & 63;
    const int wave = tid >> 6;

    // ---- Phase 0: stage edge_attr (perm-gathered, bf16) ----
    u16* ea_lds = uregion;
    for (int i = tid; i < E_TILE * 32; i += 256) {
        int e = i >> 5, c = i & 31;
        int eg = ebase + e;
        float v = 0.f;
        if (eg < E) v = edge_attr[(size_t)perm[eg] * 32 + c];
        ea_lds[e * EAS + c] = f2bf(v);
    }

    // ---- Phase 0b: edge_index/edge_sh -> SRCs, SHs(raw); keep dst/valid in regs ----
    const int ce = tid >> 2, t4 = tid & 3;   // 4 threads per edge
    bool cvalid;
    int cdst;
    {
        int eg = ebase + ce;
        int pe = (eg < E) ? perm[eg] : -1;
        cvalid = pe >= 0;
        cdst = 0;
        if (t4 == 0) {
            int srci = -1;
            float sh0 = 0.f, s1a = 0.f, s1b = 0.f, s1c = 0.f;
            if (cvalid) {
                srci = edge_index[pe];
                sh0  = edge_sh[(size_t)pe * 4 + 0];
                s1a  = edge_sh[(size_t)pe * 4 + 1];
                s1b  = edge_sh[(size_t)pe * 4 + 2];
                s1c  = edge_sh[(size_t)pe * 4 + 3];
            }
            SRCs[ce] = srci;
            SHs[ce][0] = sh0;
            SHs[ce][1] = s1a;
            SHs[ce][2] = s1b;
            SHs[ce][3] = s1c;
        }
        if (cvalid) cdst = edge_index[E + pe];
    }
    __syncthreads();

    // ---- run lengths in sorted-src tile ----
    if (tid < 64) {
        int e = tid;
        int s = SRCs[e];
        bool start = (e == 0) || (SRCs[e - 1] != s);
        int len = 0;
        if (start) {
            int end = e + 1;
            while (end < 64 && SRCs[end] == s) ++end;
            len = end - e;
        }
        RLEN[e] = len;
    }

    // ---- Phase 1: h = relu(ea @ W1 + b1) via MFMA ----
    u16 (*h_lds)[KL] = (u16(*)[KL])(uregion + 2560);
    {
        int erow = wave * 16 + (lane & 15);
        int ko1 = (lane >> 4) * 8;
        bf16x8 ea_frag = *(const bf16x8*)&ea_lds[erow * EAS + ko1];
        int r0 = wave * 16 + (lane >> 4) * 4;
#pragma unroll
        for (int nt = 0; nt < 8; ++nt) {
            int ncol = nt * 16 + (lane & 15);
            bf16x8 bfr = *(const bf16x8*)&w1t[(size_t)ncol * 32 + ko1];
            f32x4 acc = {0.f, 0.f, 0.f, 0.f};
            acc = __builtin_amdgcn_mfma_f32_16x16x32_bf16(ea_frag, bfr, acc, 0, 0, 0);
            float b = fc_b1[ncol];
#pragma unroll
            for (int r = 0; r < 4; ++r)
                h_lds[r0 + r][ncol] = f2bf(fmaxf(acc[r] + b, 0.f));
        }
        for (int i = tid; i < E_TILE * 32; i += 256) {
            int e = i >> 5, k = 128 + (i & 31);
            h_lds[e][k] = (k == 128) ? (u16)0x3F80 : (u16)0;
        }
    }
    __syncthreads();

    // ---- A fragments (2 M-frags per wave) ----
    const int mw = wave >> 1, nw = wave & 1;   // edges: mw half; N-tiles: nt = nw + 2t
    const int ko = (lane >> 4) * 8;
    bf16x8 afrag[2][5];
#pragma unroll
    for (int m = 0; m < 2; ++m) {
        int mrow = mw * 32 + m * 16 + (lane & 15);
#pragma unroll
        for (int kk = 0; kk < 5; ++kk)
            afrag[m][kk] = *(const bf16x8*)&h_lds[mrow][kk * 32 + ko];
    }
    __syncthreads();   // ea+h dead -> coef overlay may be written

    // ---- Phase 1b: gather node_attr[dst], build f32 coef tables (overlay) ----
    float* coef = (float*)uregion;
    {
        float sh0 = SHs[ce][0], s1a = SHs[ce][1], s1b = SHs[ce][2], s1c = SHs[ce][3];
        const float* na = node_attr + (size_t)cdst * 80;
        float l1c = A0C * sh0;
#pragma unroll
        for (int q = 0; q < 8; ++q) {
            int u = q * 4 + t4;
            float x = cvalid ? na[u] : 0.f;
            coef[u * CSF + ce]        = l1c * x;
            coef[(32 + u) * CSF + ce] = x;
        }
#pragma unroll
        for (int q = 0; q < 4; ++q) {
            int u = q * 4 + t4;
            float xa = cvalid ? na[32 + u * 3 + 0] : 0.f;
            float xb = cvalid ? na[32 + u * 3 + 1] : 0.f;
            float xc = cvalid ? na[32 + u * 3 + 2] : 0.f;
            coef[(64 + u * 3 + 0) * CSF + ce] = xa;
            coef[(64 + u * 3 + 1) * CSF + ce] = xb;
            coef[(64 + u * 3 + 2) * CSF + ce] = xc;
            coef[(112 + u) * CSF + ce] = A0IS3 * (xa * s1a + xb * s1b + xc * s1c);
        }
    }
    __syncthreads();

    float o0a[2][4] = {}, o0b[2][4] = {}, q2[2][4] = {}, q3[3][2][4] = {};
    const int eg4 = (lane >> 4) * 4;

    auto step = [&](const bf16x8 (&b)[5], int gnt) {
        f32x4 acc0 = {0.f, 0.f, 0.f, 0.f};
        f32x4 acc1 = {0.f, 0.f, 0.f, 0.f};
#pragma unroll
        for (int kk = 0; kk < 5; ++kk) {
            acc0 = __builtin_amdgcn_mfma_f32_16x16x32_bf16(afrag[0][kk], b[kk], acc0, 0, 0, 0);
            acc1 = __builtin_amdgcn_mfma_f32_16x16x32_bf16(afrag[1][kk], b[kk], acc1, 0, 0, 0);
        }
#pragma unroll
        for (int m = 0; m < 2; ++m) {
            const f32x4 acc = m ? acc1 : acc0;
            const int e0 = mw * 32 + m * 16 + eg4;
            if (gnt < 64) {
                int u = gnt >> 1;
                f32x4 cv = *(const f32x4*)&coef[u * CSF + e0];
                if (gnt & 1) {
#pragma unroll
                    for (int r = 0; r < 4; ++r) o0b[m][r] += cv[r] * acc[r];
                } else {
#pragma unroll
                    for (int r = 0; r < 4; ++r) o0a[m][r] += cv[r] * acc[r];
                }
            } else if (gnt < 96) {
                int u = gnt - 64;
                f32x4 cv = *(const f32x4*)&coef[(32 + u) * CSF + e0];
#pragma unroll
                for (int r = 0; r < 4; ++r) q2[m][r] += cv[r] * acc[r];
            } else if (gnt < 112) {
                int u = gnt - 96;
                f32x4 ca = *(const f32x4*)&coef[(64 + u * 3 + 0) * CSF + e0];
                f32x4 cb = *(const f32x4*)&coef[(64 + u * 3 + 1) * CSF + e0];
                f32x4 cc = *(const f32x4*)&coef[(64 + u * 3 + 2) * CSF + e0];
#pragma unroll
                for (int r = 0; r < 4; ++r) {
                    float a = acc[r];
                    q3[0][m][r] += ca[r] * a;
                    q3[1][m][r] += cb[r] * a;
                    q3[2][m][r] += cc[r] * a;
                }
            } else {
                int idx = gnt - 112;
                int u = idx >> 1;
                f32x4 cv = *(const f32x4*)&coef[(112 + u) * CSF + e0];
                if (idx & 1) {
#pragma unroll
                    for (int r = 0; r < 4; ++r) o0b[m][r] += cv[r] * acc[r];
                } else {
#pragma unroll
                    for (int r = 0; r < 4; ++r) o0a[m][r] += cv[r] * acc[r];
                }
            }
        }
    };

    // ---- Phase 2: 72 N-tiles per wave, B direct from L2, reg double-buffered, NO barriers ----
    const u16* pt = w2frag + (size_t)nw * 2560 + (size_t)lane * 8;  // nt=nw; frag stride 512 u16
    bf16x8 bA[5], bB[5];
#pragma unroll
    for (int kk = 0; kk < 5; ++kk) bA[kk] = *(const bf16x8*)(pt + kk * 512);
    for (int t = 0; t < 72; t += 2) {
#pragma unroll
        for (int kk = 0; kk < 5; ++kk) bB[kk] = *(const bf16x8*)(pt + 5120 + kk * 512);
        step(bA, nw + 2 * t);
        if (t + 2 < 72) {
#pragma unroll
            for (int kk = 0; kk < 5; ++kk) bA[kk] = *(const bf16x8*)(pt + 10240 + kk * 512);
        }
        step(bB, nw + 2 * t + 2);
        pt += 10240;
    }
    __syncthreads();   // all waves done reading coef -> tp overlay may be written

    // ---- Phase 3a: combine nw partials into tp LDS [80][TPS] ----
    float* tp = (float*)uregion;
    {
        int v = lane & 15;
        if (nw == 0) {
#pragma unroll
            for (int m = 0; m < 2; ++m)
#pragma unroll
            for (int r = 0; r < 4; ++r) {
                int e = mw * 32 + m * 16 + eg4 + r;
                float g  = A1IS3 * SHs[e][0];
                float s0 = A1IS3 * SHs[e][1];
                float s1 = A1IS3 * SHs[e][2];
                float s2 = A1IS3 * SHs[e][3];
                tp[v * TPS + e]                = o0a[m][r];
                tp[(16 + v) * TPS + e]         = o0b[m][r];
                tp[(32 + 3 * v + 0) * TPS + e] = q2[m][r] * s0 + g * q3[0][m][r];
                tp[(32 + 3 * v + 1) * TPS + e] = q2[m][r] * s1 + g * q3[1][m][r];
                tp[(32 + 3 * v + 2) * TPS + e] = q2[m][r] * s2 + g * q3[2][m][r];
            }
        }
        __syncthreads();
        if (nw == 1) {
#pragma unroll
            for (int m = 0; m < 2; ++m)
#pragma unroll
            for (int r = 0; r < 4; ++r) {
                int e = mw * 32 + m * 16 + eg4 + r;
                float g  = A1IS3 * SHs[e][0];
                float s0 = A1IS3 * SHs[e][1];
                float s1 = A1IS3 * SHs[e][2];
                float s2 = A1IS3 * SHs[e][3];
                tp[v * TPS + e]                += o0a[m][r];
                tp[(16 + v) * TPS + e]         += o0b[m][r];
                tp[(32 + 3 * v + 0) * TPS + e] += q2[m][r] * s0 + g * q3[0][m][r];
                tp[(32 + 3 * v + 1) * TPS + e] += q2[m][r] * s1 + g * q3[1][m][r];
                tp[(32 + 3 * v + 2) * TPS + e] += q2[m][r] * s2 + g * q3[2][m][r];
            }
        }
    }
    __syncthreads();

    // ---- Phase 3b: per-run serial sum + one atomic per (run, component) ----
    for (int i = tid; i < E_TILE * 80; i += 256) {
        int e = i & 63, c = i >> 6;
        int len = RLEN[e];
        if (len > 0 && SRCs[e] >= 0) {
            float s = 0.f;
            for (int k = 0; k < len; ++k) s += tp[c * TPS + e + k];
            unsafeAtomicAdd(&out[(size_t)SRCs[e] * 80 + c], s);
        }
    }
}

extern "C" void kernel_launch(void* const* d_in, const int* in_sizes, int n_in,
                              void* d_out, int out_size, void* d_ws, size_t ws_size,
                              hipStream_t stream) {
    const float* node_attr  = (const float*)d_in[0];
    const int*   edge_index = (const int*)d_in[1];
    const float* edge_attr  = (const float*)d_in[2];
    const float* edge_sh    = (const float*)d_in[3];
    const float* fc_w1      = (const float*)d_in[4];
    const float* fc_b1      = (const float*)d_in[5];
    const float* fc_w2      = (const float*)d_in[6];
    const float* fc_b2      = (const float*)d_in[7];
    int N = in_sizes[0] / 80;
    int E = in_sizes[1] / 2;
    float* out = (float*)d_out;

    int* cnt  = (int*)d_ws;
    int* cur  = cnt + N;
    int* perm = cur + N;
    u16* w2frag = (u16*)(perm + E);              // 460800 u16
    u16* w1t    = w2frag + (size_t)NTILES * 5 * 64 * 8;

    hipMemsetAsync(out, 0, (size_t)N * 80 * 4, stream);
    hipMemsetAsync(cnt, 0, (size_t)N * 4, stream);

    int prep_total = NTILES * 5 * 64 * 8 + 128 * 32;
    prep_w<<<(prep_total + 255) / 256, 256, 0, stream>>>(fc_w2, fc_b2, fc_w1, w2frag, w1t);
    count_k<<<(E + 255) / 256, 256, 0, stream>>>(edge_index, E, cnt);
    scan_k<<<1, 1024, 0, stream>>>(cnt, cur, N);
    scatter_k<<<(E + 255) / 256, 256, 0, stream>>>(edge_index, E, cur, perm);
    tpcl_main<<<(E + E_TILE - 1) / E_TILE, 256, 0, stream>>>(
        node_attr, edge_index, edge_attr, edge_sh, w1t, fc_b1, w2frag, perm, out, N, E);
    finalize_k<<<(N * 80 + 255) / 256, 256, 0, stream>>>(out, cnt, N * 80);
}

// Round 7
// 518.734 us; speedup vs baseline: 4.8267x; 4.8267x over previous
//
#include <hip/hip_runtime.h>

typedef unsigned short u16;
typedef unsigned int u32;
typedef __attribute__((ext_vector_type(8))) __bf16 bf16x8;
typedef __attribute__((ext_vector_type(4))) float f32x4;

#define E_TILE 64
#define KP 160      // padded K: 128 h + 1 bias-one + 31 zeros
#define KL 168      // h LDS row stride in u16
#define EAS 40      // ea LDS row stride in u16
#define WNTOT 2304
#define NTILES 144  // 2304 / 16
#define CSF 68      // f32 coef stride
#define TPS 73      // tp scratch stride in f32

#define A0C   0.14433756729740643f   /* sqrt(1/48) */
#define A0IS3 0.08333333333333333f   /* A0/sqrt(3) = 1/12 */
#define A1IS3 0.14433756729740643f   /* (1/4)/sqrt(3) */

__device__ inline u16 f2bf(float f) {
    union { float f; u32 u; } v; v.f = f;
    u32 u = v.u;
    return (u16)((u + 0x7FFFu + ((u >> 16) & 1u)) >> 16);  // RNE
}

// w2frag: fragment-ordered W2T. idx = ((nt*5 + kk)*64 + lane)*8 + j
//   n = nt*16 + (lane&15); k = kk*32 + (lane>>4)*8 + j
//   value = k<128 ? W2[k][n] : (k==128 ? b2[n] : 0)
// w1t[n][k] = W1[k][n]
__global__ void prep_w(const float* __restrict__ w2, const float* __restrict__ b2,
                       const float* __restrict__ w1,
                       u16* __restrict__ w2frag, u16* __restrict__ w1t) {
    int idx = blockIdx.x * 256 + threadIdx.x;
    const int tot2 = NTILES * 5 * 64 * 8;   // 460800
    if (idx < tot2) {
        int j = idx & 7;
        int l = (idx >> 3) & 63;
        int f = idx >> 9;
        int nt = f / 5, kk = f - nt * 5;
        int n = nt * 16 + (l & 15);
        int k = kk * 32 + (l >> 4) * 8 + j;
        float v = 0.f;
        if (k < 128) v = w2[(size_t)k * WNTOT + n];
        else if (k == 128) v = b2[n];
        w2frag[idx] = f2bf(v);
    } else {
        int j = idx - tot2;
        if (j < 128 * 32) {
            int n = j >> 5, k = j & 31;
            w1t[j] = f2bf(w1[k * 128 + n]);
        }
    }
}

__global__ void count_k(const int* __restrict__ src, int E, int* __restrict__ cnt) {
    int i = blockIdx.x * 256 + threadIdx.x;
    if (i < E) atomicAdd(&cnt[src[i]], 1);
}

// single block, 1024 threads: cur = exclusive-prefix-sum(cnt)
__global__ void scan_k(const int* __restrict__ cnt, int* __restrict__ cur, int N) {
    __shared__ int part[1024];
    int t = threadIdx.x;
    int S = (N + 1023) >> 10;
    int lo = t * S; if (lo > N) lo = N;
    int hi = lo + S; if (hi > N) hi = N;
    int s = 0;
    for (int i = lo; i < hi; ++i) s += cnt[i];
    part[t] = s;
    __syncthreads();
    for (int d = 1; d < 1024; d <<= 1) {
        int add = (t >= d) ? part[t - d] : 0;
        __syncthreads();
        part[t] += add;
        __syncthreads();
    }
    int run = part[t] - s;   // exclusive
    for (int i = lo; i < hi; ++i) { cur[i] = run; run += cnt[i]; }
}

__global__ void scatter_k(const int* __restrict__ ei, int E,
                          int* __restrict__ cur, int* __restrict__ perm) {
    int e = blockIdx.x * 256 + threadIdx.x;
    if (e < E) {
        int s = ei[e];
        int p = atomicAdd(&cur[s], 1);
        perm[p] = e;
    }
}

__global__ void finalize_k(float* __restrict__ out, const int* __restrict__ cnt, int total) {
    int i = blockIdx.x * 256 + threadIdx.x;
    if (i >= total) return;
    float c = (float)cnt[i / 80];
    out[i] /= fmaxf(c, 1.0f);
}

__global__ __launch_bounds__(256, 2)   // (256,4) clamps VGPR to 64 -> catastrophic spill (r6)
void tpcl_main(const float* __restrict__ node_attr,
               const int* __restrict__ edge_index,
               const float* __restrict__ edge_attr,
               const float* __restrict__ edge_sh,
               const u16* __restrict__ w1t,
               const float* __restrict__ fc_b1,
               const u16* __restrict__ w2frag,
               const int* __restrict__ perm,
               float* __restrict__ out,
               int N, int E)
{
    // Phase-unioned region (34816 B = max of the three):
    //   phase 0/1 : ea [64][EAS] u16 (5120 B) + h [64][KL] u16 at u16-ofs 2560 (21504 B)
    //   phase 1b/2: coef f32 [128][CSF] (34816 B)  rows: 0..31 L1, 32..63 X0, 64..111 X1, 112..127 L4
    //   phase 3   : tp f32 [80][TPS] (23360 B)
    // 36352 B total LDS -> 4 blocks/CU
    alignas(16) __shared__ u16 uregion[17408];
    __shared__ float SHs[E_TILE][4];   // RAW sh0, s1a, s1b, s1c
    __shared__ int SRCs[E_TILE];
    __shared__ int RLEN[E_TILE];

    const int tid = threadIdx.x;
    const int ebase = blockIdx.x * E_TILE;
    const int lane = tid & 63;
    const int wave = tid >> 6;

    // ---- Phase 0: stage edge_attr (perm-gathered, bf16) ----
    u16* ea_lds = uregion;
    for (int i = tid; i < E_TILE * 32; i += 256) {
        int e = i >> 5, c = i & 31;
        int eg = ebase + e;
        float v = 0.f;
        if (eg < E) v = edge_attr[(size_t)perm[eg] * 32 + c];
        ea_lds[e * EAS + c] = f2bf(v);
    }

    // ---- Phase 0b: edge_index/edge_sh -> SRCs, SHs(raw); keep dst/valid in regs ----
    const int ce = tid >> 2, t4 = tid & 3;   // 4 threads per edge
    bool cvalid;
    int cdst;
    {
        int eg = ebase + ce;
        int pe = (eg < E) ? perm[eg] : -1;
        cvalid = pe >= 0;
        cdst = 0;
        if (t4 == 0) {
            int srci = -1;
            float sh0 = 0.f, s1a = 0.f, s1b = 0.f, s1c = 0.f;
            if (cvalid) {
                srci = edge_index[pe];
                sh0  = edge_sh[(size_t)pe * 4 + 0];
                s1a  = edge_sh[(size_t)pe * 4 + 1];
                s1b  = edge_sh[(size_t)pe * 4 + 2];
                s1c  = edge_sh[(size_t)pe * 4 + 3];
            }
            SRCs[ce] = srci;
            SHs[ce][0] = sh0;
            SHs[ce][1] = s1a;
            SHs[ce][2] = s1b;
            SHs[ce][3] = s1c;
        }
        if (cvalid) cdst = edge_index[E + pe];
    }
    __syncthreads();

    // ---- run lengths in sorted-src tile ----
    if (tid < 64) {
        int e = tid;
        int s = SRCs[e];
        bool start = (e == 0) || (SRCs[e - 1] != s);
        int len = 0;
        if (start) {
            int end = e + 1;
            while (end < 64 && SRCs[end] == s) ++end;
            len = end - e;
        }
        RLEN[e] = len;
    }

    // ---- Phase 1: h = relu(ea @ W1 + b1) via MFMA ----
    u16 (*h_lds)[KL] = (u16(*)[KL])(uregion + 2560);
    {
        int erow = wave * 16 + (lane & 15);
        int ko1 = (lane >> 4) * 8;
        bf16x8 ea_frag = *(const bf16x8*)&ea_lds[erow * EAS + ko1];
        int r0 = wave * 16 + (lane >> 4) * 4;
#pragma unroll
        for (int nt = 0; nt < 8; ++nt) {
            int ncol = nt * 16 + (lane & 15);
            bf16x8 bfr = *(const bf16x8*)&w1t[(size_t)ncol * 32 + ko1];
            f32x4 acc = {0.f, 0.f, 0.f, 0.f};
            acc = __builtin_amdgcn_mfma_f32_16x16x32_bf16(ea_frag, bfr, acc, 0, 0, 0);
            float b = fc_b1[ncol];
#pragma unroll
            for (int r = 0; r < 4; ++r)
                h_lds[r0 + r][ncol] = f2bf(fmaxf(acc[r] + b, 0.f));
        }
        for (int i = tid; i < E_TILE * 32; i += 256) {
            int e = i >> 5, k = 128 + (i & 31);
            h_lds[e][k] = (k == 128) ? (u16)0x3F80 : (u16)0;
        }
    }
    __syncthreads();

    // ---- A fragments (2 M-frags per wave) ----
    const int mw = wave >> 1, nw = wave & 1;   // edges: mw half; N-tiles: nt = nw + 2t
    const int ko = (lane >> 4) * 8;
    bf16x8 afrag[2][5];
#pragma unroll
    for (int m = 0; m < 2; ++m) {
        int mrow = mw * 32 + m * 16 + (lane & 15);
#pragma unroll
        for (int kk = 0; kk < 5; ++kk)
            afrag[m][kk] = *(const bf16x8*)&h_lds[mrow][kk * 32 + ko];
    }
    __syncthreads();   // ea+h dead -> coef overlay may be written

    // ---- Phase 1b: gather node_attr[dst], build f32 coef tables (overlay) ----
    float* coef = (float*)uregion;
    {
        float sh0 = SHs[ce][0], s1a = SHs[ce][1], s1b = SHs[ce][2], s1c = SHs[ce][3];
        const float* na = node_attr + (size_t)cdst * 80;
        float l1c = A0C * sh0;
#pragma unroll
        for (int q = 0; q < 8; ++q) {
            int u = q * 4 + t4;
            float x = cvalid ? na[u] : 0.f;
            coef[u * CSF + ce]        = l1c * x;
            coef[(32 + u) * CSF + ce] = x;
        }
#pragma unroll
        for (int q = 0; q < 4; ++q) {
            int u = q * 4 + t4;
            float xa = cvalid ? na[32 + u * 3 + 0] : 0.f;
            float xb = cvalid ? na[32 + u * 3 + 1] : 0.f;
            float xc = cvalid ? na[32 + u * 3 + 2] : 0.f;
            coef[(64 + u * 3 + 0) * CSF + ce] = xa;
            coef[(64 + u * 3 + 1) * CSF + ce] = xb;
            coef[(64 + u * 3 + 2) * CSF + ce] = xc;
            coef[(112 + u) * CSF + ce] = A0IS3 * (xa * s1a + xb * s1b + xc * s1c);
        }
    }
    __syncthreads();

    float o0a[2][4] = {}, o0b[2][4] = {}, q2[2][4] = {}, q3[3][2][4] = {};
    const int eg4 = (lane >> 4) * 4;

    auto step = [&](const bf16x8 (&b)[5], int gnt) {
        f32x4 acc0 = {0.f, 0.f, 0.f, 0.f};
        f32x4 acc1 = {0.f, 0.f, 0.f, 0.f};
#pragma unroll
        for (int kk = 0; kk < 5; ++kk) {
            acc0 = __builtin_amdgcn_mfma_f32_16x16x32_bf16(afrag[0][kk], b[kk], acc0, 0, 0, 0);
            acc1 = __builtin_amdgcn_mfma_f32_16x16x32_bf16(afrag[1][kk], b[kk], acc1, 0, 0, 0);
        }
#pragma unroll
        for (int m = 0; m < 2; ++m) {
            const f32x4 acc = m ? acc1 : acc0;
            const int e0 = mw * 32 + m * 16 + eg4;
            if (gnt < 64) {
                int u = gnt >> 1;
                f32x4 cv = *(const f32x4*)&coef[u * CSF + e0];
                if (gnt & 1) {
#pragma unroll
                    for (int r = 0; r < 4; ++r) o0b[m][r] += cv[r] * acc[r];
                } else {
#pragma unroll
                    for (int r = 0; r < 4; ++r) o0a[m][r] += cv[r] * acc[r];
                }
            } else if (gnt < 96) {
                int u = gnt - 64;
                f32x4 cv = *(const f32x4*)&coef[(32 + u) * CSF + e0];
#pragma unroll
                for (int r = 0; r < 4; ++r) q2[m][r] += cv[r] * acc[r];
            } else if (gnt < 112) {
                int u = gnt - 96;
                f32x4 ca = *(const f32x4*)&coef[(64 + u * 3 + 0) * CSF + e0];
                f32x4 cb = *(const f32x4*)&coef[(64 + u * 3 + 1) * CSF + e0];
                f32x4 cc = *(const f32x4*)&coef[(64 + u * 3 + 2) * CSF + e0];
#pragma unroll
                for (int r = 0; r < 4; ++r) {
                    float a = acc[r];
                    q3[0][m][r] += ca[r] * a;
                    q3[1][m][r] += cb[r] * a;
                    q3[2][m][r] += cc[r] * a;
                }
            } else {
                int idx = gnt - 112;
                int u = idx >> 1;
                f32x4 cv = *(const f32x4*)&coef[(112 + u) * CSF + e0];
                if (idx & 1) {
#pragma unroll
                    for (int r = 0; r < 4; ++r) o0b[m][r] += cv[r] * acc[r];
                } else {
#pragma unroll
                    for (int r = 0; r < 4; ++r) o0a[m][r] += cv[r] * acc[r];
                }
            }
        }
    };

    // ---- Phase 2: 72 N-tiles per wave, B direct from L2, reg double-buffered, NO barriers ----
    const u16* pt = w2frag + (size_t)nw * 2560 + (size_t)lane * 8;  // nt=nw; frag stride 512 u16
    bf16x8 bA[5], bB[5];
#pragma unroll
    for (int kk = 0; kk < 5; ++kk) bA[kk] = *(const bf16x8*)(pt + kk * 512);
    for (int t = 0; t < 72; t += 2) {
#pragma unroll
        for (int kk = 0; kk < 5; ++kk) bB[kk] = *(const bf16x8*)(pt + 5120 + kk * 512);
        step(bA, nw + 2 * t);
        if (t + 2 < 72) {
#pragma unroll
            for (int kk = 0; kk < 5; ++kk) bA[kk] = *(const bf16x8*)(pt + 10240 + kk * 512);
        }
        step(bB, nw + 2 * t + 2);
        pt += 10240;
    }
    __syncthreads();   // all waves done reading coef -> tp overlay may be written

    // ---- Phase 3a: combine nw partials into tp LDS [80][TPS] ----
    float* tp = (float*)uregion;
    {
        int v = lane & 15;
        if (nw == 0) {
#pragma unroll
            for (int m = 0; m < 2; ++m)
#pragma unroll
            for (int r = 0; r < 4; ++r) {
                int e = mw * 32 + m * 16 + eg4 + r;
                float g  = A1IS3 * SHs[e][0];
                float s0 = A1IS3 * SHs[e][1];
                float s1 = A1IS3 * SHs[e][2];
                float s2 = A1IS3 * SHs[e][3];
                tp[v * TPS + e]                = o0a[m][r];
                tp[(16 + v) * TPS + e]         = o0b[m][r];
                tp[(32 + 3 * v + 0) * TPS + e] = q2[m][r] * s0 + g * q3[0][m][r];
                tp[(32 + 3 * v + 1) * TPS + e] = q2[m][r] * s1 + g * q3[1][m][r];
                tp[(32 + 3 * v + 2) * TPS + e] = q2[m][r] * s2 + g * q3[2][m][r];
            }
        }
        __syncthreads();
        if (nw == 1) {
#pragma unroll
            for (int m = 0; m < 2; ++m)
#pragma unroll
            for (int r = 0; r < 4; ++r) {
                int e = mw * 32 + m * 16 + eg4 + r;
                float g  = A1IS3 * SHs[e][0];
                float s0 = A1IS3 * SHs[e][1];
                float s1 = A1IS3 * SHs[e][2];
                float s2 = A1IS3 * SHs[e][3];
                tp[v * TPS + e]                += o0a[m][r];
                tp[(16 + v) * TPS + e]         += o0b[m][r];
                tp[(32 + 3 * v + 0) * TPS + e] += q2[m][r] * s0 + g * q3[0][m][r];
                tp[(32 + 3 * v + 1) * TPS + e] += q2[m][r] * s1 + g * q3[1][m][r];
                tp[(32 + 3 * v + 2) * TPS + e] += q2[m][r] * s2 + g * q3[2][m][r];
            }
        }
    }
    __syncthreads();

    // ---- Phase 3b: per-run serial sum + one atomic per (run, component) ----
    for (int i = tid; i < E_TILE * 80; i += 256) {
        int e = i & 63, c = i >> 6;
        int len = RLEN[e];
        if (len > 0 && SRCs[e] >= 0) {
            float s = 0.f;
            for (int k = 0; k < len; ++k) s += tp[c * TPS + e + k];
            unsafeAtomicAdd(&out[(size_t)SRCs[e] * 80 + c], s);
        }
    }
}

extern "C" void kernel_launch(void* const* d_in, const int* in_sizes, int n_in,
                              void* d_out, int out_size, void* d_ws, size_t ws_size,
                              hipStream_t stream) {
    const float* node_attr  = (const float*)d_in[0];
    const int*   edge_index = (const int*)d_in[1];
    const float* edge_attr  = (const float*)d_in[2];
    const float* edge_sh    = (const float*)d_in[3];
    const float* fc_w1      = (const float*)d_in[4];
    const float* fc_b1      = (const float*)d_in[5];
    const float* fc_w2      = (const float*)d_in[6];
    const float* fc_b2      = (const float*)d_in[7];
    int N = in_sizes[0] / 80;
    int E = in_sizes[1] / 2;
    float* out = (float*)d_out;

    int* cnt  = (int*)d_ws;
    int* cur  = cnt + N;
    int* perm = cur + N;
    u16* w2frag = (u16*)(perm + E);              // 460800 u16
    u16* w1t    = w2frag + (size_t)NTILES * 5 * 64 * 8;

    hipMemsetAsync(out, 0, (size_t)N * 80 * 4, stream);
    hipMemsetAsync(cnt, 0, (size_t)N * 4, stream);

    int prep_total = NTILES * 5 * 64 * 8 + 128 * 32;
    prep_w<<<(prep_total + 255) / 256, 256, 0, stream>>>(fc_w2, fc_b2, fc_w1, w2frag, w1t);
    count_k<<<(E + 255) / 256, 256, 0, stream>>>(edge_index, E, cnt);
    scan_k<<<1, 1024, 0, stream>>>(cnt, cur, N);
    scatter_k<<<(E + 255) / 256, 256, 0, stream>>>(edge_index, E, cur, perm);
    tpcl_main<<<(E + E_TILE - 1) / E_TILE, 256, 0, stream>>>(
        node_attr, edge_index, edge_attr, edge_sh, w1t, fc_b1, w2frag, perm, out, N, E);
    finalize_k<<<(N * 80 + 255) / 256, 256, 0, stream>>>(out, cnt, N * 80);
}

// Round 8
// 458.526 us; speedup vs baseline: 5.4604x; 1.1313x over previous
//
#include <hip/hip_runtime.h>

typedef unsigned short u16;
typedef unsigned int u32;
typedef __attribute__((ext_vector_type(8))) __bf16 bf16x8;
typedef __attribute__((ext_vector_type(4))) float f32x4;

#define E_TILE 64
#define KL 136      // h LDS row stride in u16 (272B = 17*16B)
#define EAS 40      // ea LDS row stride in u16
#define WNTOT 2304
#define NTILES 144  // 2304 / 16
#define CSF 68      // f32 coef stride
#define TPS 73      // tp scratch stride in f32

#define A0C   0.14433756729740643f   /* sqrt(1/48) */
#define A0IS3 0.08333333333333333f   /* A0/sqrt(3) = 1/12 */
#define A1IS3 0.14433756729740643f   /* (1/4)/sqrt(3) */

__device__ inline u16 f2bf(float f) {
    union { float f; u32 u; } v; v.f = f;
    u32 u = v.u;
    return (u16)((u + 0x7FFFu + ((u >> 16) & 1u)) >> 16);  // RNE
}

// w2frag: fragment-ordered W2T, K=128 (no bias row).
//   idx = ((nt*4 + kk)*64 + lane)*8 + j
//   n = nt*16 + (lane&15); k = kk*32 + (lane>>4)*8 + j;  value = W2[k][n]
// w1t[n][k] = W1[k][n]
__global__ void prep_w(const float* __restrict__ w2, const float* __restrict__ w1,
                       u16* __restrict__ w2frag, u16* __restrict__ w1t) {
    int idx = blockIdx.x * 256 + threadIdx.x;
    const int tot2 = NTILES * 4 * 64 * 8;   // 294912
    if (idx < tot2) {
        int j = idx & 7;
        int l = (idx >> 3) & 63;
        int f = idx >> 9;
        int nt = f >> 2, kk = f & 3;
        int n = nt * 16 + (l & 15);
        int k = kk * 32 + (l >> 4) * 8 + j;
        w2frag[idx] = f2bf(w2[(size_t)k * WNTOT + n]);
    } else {
        int j = idx - tot2;
        if (j < 128 * 32) {
            int n = j >> 5, k = j & 31;
            w1t[j] = f2bf(w1[k * 128 + n]);
        }
    }
}

__global__ void count_k(const int* __restrict__ src, int E, int* __restrict__ cnt) {
    int i = blockIdx.x * 256 + threadIdx.x;
    if (i < E) atomicAdd(&cnt[src[i]], 1);
}

// single block, 1024 threads: cur = exclusive-prefix-sum(cnt)
__global__ void scan_k(const int* __restrict__ cnt, int* __restrict__ cur, int N) {
    __shared__ int part[1024];
    int t = threadIdx.x;
    int S = (N + 1023) >> 10;
    int lo = t * S; if (lo > N) lo = N;
    int hi = lo + S; if (hi > N) hi = N;
    int s = 0;
    for (int i = lo; i < hi; ++i) s += cnt[i];
    part[t] = s;
    __syncthreads();
    for (int d = 1; d < 1024; d <<= 1) {
        int add = (t >= d) ? part[t - d] : 0;
        __syncthreads();
        part[t] += add;
        __syncthreads();
    }
    int run = part[t] - s;   // exclusive
    for (int i = lo; i < hi; ++i) { cur[i] = run; run += cnt[i]; }
}

__global__ void scatter_k(const int* __restrict__ ei, int E,
                          int* __restrict__ cur, int* __restrict__ perm) {
    int e = blockIdx.x * 256 + threadIdx.x;
    if (e < E) {
        int s = ei[e];
        int p = atomicAdd(&cur[s], 1);
        perm[p] = e;
    }
}

__global__ void finalize_k(float* __restrict__ out, const int* __restrict__ cnt, int total) {
    int i = blockIdx.x * 256 + threadIdx.x;
    if (i >= total) return;
    float c = (float)cnt[i / 80];
    out[i] /= fmaxf(c, 1.0f);
}

__global__ __launch_bounds__(256, 4)   // total reg budget 128 (arch+acc); live set ~120 fits
void tpcl_main(const float* __restrict__ node_attr,
               const int* __restrict__ edge_index,
               const float* __restrict__ edge_attr,
               const float* __restrict__ edge_sh,
               const u16* __restrict__ w1t,
               const float* __restrict__ fc_b1,
               const float* __restrict__ fc_b2,
               const u16* __restrict__ w2frag,
               const int* __restrict__ perm,
               float* __restrict__ out,
               int N, int E)
{
    // Phase-unioned region (34816 B = max of the three):
    //   phase 0/1 : ea [64][EAS] u16 (5120 B) + h [64][KL] u16 at u16-ofs 2560 (17408 B)
    //   phase 1b/2: coef f32 [128][CSF] (34816 B)  rows: 0..31 L1, 32..63 X0, 64..111 X1, 112..127 L4
    //   phase 3   : tp f32 [80][TPS] (23360 B)
    // 36352 B total LDS -> 4 blocks/CU
    alignas(16) __shared__ u16 uregion[17408];
    __shared__ float SHs[E_TILE][4];   // RAW sh0, s1a, s1b, s1c
    __shared__ int SRCs[E_TILE];
    __shared__ int RLEN[E_TILE];

    const int tid = threadIdx.x;
    const int ebase = blockIdx.x * E_TILE;
    const int lane = tid & 63;
    const int wave = tid >> 6;

    // ---- Phase 0: stage edge_attr (perm-gathered, bf16) ----
    u16* ea_lds = uregion;
    for (int i = tid; i < E_TILE * 32; i += 256) {
        int e = i >> 5, c = i & 31;
        int eg = ebase + e;
        float v = 0.f;
        if (eg < E) v = edge_attr[(size_t)perm[eg] * 32 + c];
        ea_lds[e * EAS + c] = f2bf(v);
    }

    // ---- Phase 0b: edge_index/edge_sh -> SRCs, SHs(raw); keep dst/valid in regs ----
    const int ce = tid >> 2, t4 = tid & 3;   // 4 threads per edge
    bool cvalid;
    int cdst;
    {
        int eg = ebase + ce;
        int pe = (eg < E) ? perm[eg] : -1;
        cvalid = pe >= 0;
        cdst = 0;
        if (t4 == 0) {
            int srci = -1;
            float sh0 = 0.f, s1a = 0.f, s1b = 0.f, s1c = 0.f;
            if (cvalid) {
                srci = edge_index[pe];
                sh0  = edge_sh[(size_t)pe * 4 + 0];
                s1a  = edge_sh[(size_t)pe * 4 + 1];
                s1b  = edge_sh[(size_t)pe * 4 + 2];
                s1c  = edge_sh[(size_t)pe * 4 + 3];
            }
            SRCs[ce] = srci;
            SHs[ce][0] = sh0;
            SHs[ce][1] = s1a;
            SHs[ce][2] = s1b;
            SHs[ce][3] = s1c;
        }
        if (cvalid) cdst = edge_index[E + pe];
    }
    __syncthreads();

    // ---- run lengths in sorted-src tile ----
    if (tid < 64) {
        int e = tid;
        int s = SRCs[e];
        bool start = (e == 0) || (SRCs[e - 1] != s);
        int len = 0;
        if (start) {
            int end = e + 1;
            while (end < 64 && SRCs[end] == s) ++end;
            len = end - e;
        }
        RLEN[e] = len;
    }

    // ---- Phase 1: h = relu(ea @ W1 + b1) via MFMA ----
    u16 (*h_lds)[KL] = (u16(*)[KL])(uregion + 2560);
    {
        int erow = wave * 16 + (lane & 15);
        int ko1 = (lane >> 4) * 8;
        bf16x8 ea_frag = *(const bf16x8*)&ea_lds[erow * EAS + ko1];
        int r0 = wave * 16 + (lane >> 4) * 4;
#pragma unroll
        for (int nt = 0; nt < 8; ++nt) {
            int ncol = nt * 16 + (lane & 15);
            bf16x8 bfr = *(const bf16x8*)&w1t[(size_t)ncol * 32 + ko1];
            f32x4 acc = {0.f, 0.f, 0.f, 0.f};
            acc = __builtin_amdgcn_mfma_f32_16x16x32_bf16(ea_frag, bfr, acc, 0, 0, 0);
            float b = fc_b1[ncol];
#pragma unroll
            for (int r = 0; r < 4; ++r)
                h_lds[r0 + r][ncol] = f2bf(fmaxf(acc[r] + b, 0.f));
        }
    }
    __syncthreads();

    // ---- A fragments (2 M-frags per wave, K=128 -> 4 chunks) ----
    const int mw = wave >> 1, nw = wave & 1;   // edges: mw half; N-tiles: nt = nw + 2t
    const int ko = (lane >> 4) * 8;
    bf16x8 afrag[2][4];
#pragma unroll
    for (int m = 0; m < 2; ++m) {
        int mrow = mw * 32 + m * 16 + (lane & 15);
#pragma unroll
        for (int kk = 0; kk < 4; ++kk)
            afrag[m][kk] = *(const bf16x8*)&h_lds[mrow][kk * 32 + ko];
    }
    __syncthreads();   // ea+h dead -> coef overlay may be written

    // ---- Phase 1b: gather node_attr[dst], build f32 coef tables (overlay) ----
    float* coef = (float*)uregion;
    {
        float sh0 = SHs[ce][0], s1a = SHs[ce][1], s1b = SHs[ce][2], s1c = SHs[ce][3];
        const float* na = node_attr + (size_t)cdst * 80;
        float l1c = A0C * sh0;
#pragma unroll
        for (int q = 0; q < 8; ++q) {
            int u = q * 4 + t4;
            float x = cvalid ? na[u] : 0.f;
            coef[u * CSF + ce]        = l1c * x;
            coef[(32 + u) * CSF + ce] = x;
        }
#pragma unroll
        for (int q = 0; q < 4; ++q) {
            int u = q * 4 + t4;
            float xa = cvalid ? na[32 + u * 3 + 0] : 0.f;
            float xb = cvalid ? na[32 + u * 3 + 1] : 0.f;
            float xc = cvalid ? na[32 + u * 3 + 2] : 0.f;
            coef[(64 + u * 3 + 0) * CSF + ce] = xa;
            coef[(64 + u * 3 + 1) * CSF + ce] = xb;
            coef[(64 + u * 3 + 2) * CSF + ce] = xc;
            coef[(112 + u) * CSF + ce] = A0IS3 * (xa * s1a + xb * s1b + xc * s1c);
        }
    }
    __syncthreads();

    float o0a[2][4] = {}, o0b[2][4] = {}, q2[2][4] = {}, q3[3][2][4] = {};
    const int eg4 = (lane >> 4) * 4;

    // ---- Phase 2: 72 N-tiles per wave, single-buffered B direct from L2, NO barriers ----
    const u16* pt = w2frag + (size_t)nw * 2048 + (size_t)lane * 8;  // tile stride 2048 u16
    for (int t = 0; t < 72; ++t) {
        const int gnt = nw + 2 * t;
        bf16x8 bA[4];
#pragma unroll
        for (int kk = 0; kk < 4; ++kk) bA[kk] = *(const bf16x8*)(pt + kk * 512);
        pt += 4096;
        const float b2v = fc_b2[gnt * 16 + (lane & 15)];

        f32x4 acc0 = {0.f, 0.f, 0.f, 0.f};
        f32x4 acc1 = {0.f, 0.f, 0.f, 0.f};
#pragma unroll
        for (int kk = 0; kk < 4; ++kk) {
            acc0 = __builtin_amdgcn_mfma_f32_16x16x32_bf16(afrag[0][kk], bA[kk], acc0, 0, 0, 0);
            acc1 = __builtin_amdgcn_mfma_f32_16x16x32_bf16(afrag[1][kk], bA[kk], acc1, 0, 0, 0);
        }
#pragma unroll
        for (int m = 0; m < 2; ++m) {
            const f32x4 accr = m ? acc1 : acc0;
            const int e0 = mw * 32 + m * 16 + eg4;
            float av[4];
#pragma unroll
            for (int r = 0; r < 4; ++r) av[r] = accr[r] + b2v;
            if (gnt < 64) {
                int u = gnt >> 1;
                f32x4 cv = *(const f32x4*)&coef[u * CSF + e0];
                if (gnt & 1) {
#pragma unroll
                    for (int r = 0; r < 4; ++r) o0b[m][r] += cv[r] * av[r];
                } else {
#pragma unroll
                    for (int r = 0; r < 4; ++r) o0a[m][r] += cv[r] * av[r];
                }
            } else if (gnt < 96) {
                int u = gnt - 64;
                f32x4 cv = *(const f32x4*)&coef[(32 + u) * CSF + e0];
#pragma unroll
                for (int r = 0; r < 4; ++r) q2[m][r] += cv[r] * av[r];
            } else if (gnt < 112) {
                int u = gnt - 96;
                f32x4 ca = *(const f32x4*)&coef[(64 + u * 3 + 0) * CSF + e0];
                f32x4 cb = *(const f32x4*)&coef[(64 + u * 3 + 1) * CSF + e0];
                f32x4 cc = *(const f32x4*)&coef[(64 + u * 3 + 2) * CSF + e0];
#pragma unroll
                for (int r = 0; r < 4; ++r) {
                    float a = av[r];
                    q3[0][m][r] += ca[r] * a;
                    q3[1][m][r] += cb[r] * a;
                    q3[2][m][r] += cc[r] * a;
                }
            } else {
                int idx = gnt - 112;
                int u = idx >> 1;
                f32x4 cv = *(const f32x4*)&coef[(112 + u) * CSF + e0];
                if (idx & 1) {
#pragma unroll
                    for (int r = 0; r < 4; ++r) o0b[m][r] += cv[r] * av[r];
                } else {
#pragma unroll
                    for (int r = 0; r < 4; ++r) o0a[m][r] += cv[r] * av[r];
                }
            }
        }
    }
    __syncthreads();   // all waves done reading coef -> tp overlay may be written

    // ---- Phase 3a: combine nw partials into tp LDS [80][TPS] ----
    float* tp = (float*)uregion;
    {
        int v = lane & 15;
        if (nw == 0) {
#pragma unroll
            for (int m = 0; m < 2; ++m)
#pragma unroll
            for (int r = 0; r < 4; ++r) {
                int e = mw * 32 + m * 16 + eg4 + r;
                float g  = A1IS3 * SHs[e][0];
                float s0 = A1IS3 * SHs[e][1];
                float s1 = A1IS3 * SHs[e][2];
                float s2 = A1IS3 * SHs[e][3];
                tp[v * TPS + e]                = o0a[m][r];
                tp[(16 + v) * TPS + e]         = o0b[m][r];
                tp[(32 + 3 * v + 0) * TPS + e] = q2[m][r] * s0 + g * q3[0][m][r];
                tp[(32 + 3 * v + 1) * TPS + e] = q2[m][r] * s1 + g * q3[1][m][r];
                tp[(32 + 3 * v + 2) * TPS + e] = q2[m][r] * s2 + g * q3[2][m][r];
            }
        }
        __syncthreads();
        if (nw == 1) {
#pragma unroll
            for (int m = 0; m < 2; ++m)
#pragma unroll
            for (int r = 0; r < 4; ++r) {
                int e = mw * 32 + m * 16 + eg4 + r;
                float g  = A1IS3 * SHs[e][0];
                float s0 = A1IS3 * SHs[e][1];
                float s1 = A1IS3 * SHs[e][2];
                float s2 = A1IS3 * SHs[e][3];
                tp[v * TPS + e]                += o0a[m][r];
                tp[(16 + v) * TPS + e]         += o0b[m][r];
                tp[(32 + 3 * v + 0) * TPS + e] += q2[m][r] * s0 + g * q3[0][m][r];
                tp[(32 + 3 * v + 1) * TPS + e] += q2[m][r] * s1 + g * q3[1][m][r];
                tp[(32 + 3 * v + 2) * TPS + e] += q2[m][r] * s2 + g * q3[2][m][r];
            }
        }
    }
    __syncthreads();

    // ---- Phase 3b: per-run serial sum + one atomic per (run, component) ----
    for (int i = tid; i < E_TILE * 80; i += 256) {
        int e = i & 63, c = i >> 6;
        int len = RLEN[e];
        if (len > 0 && SRCs[e] >= 0) {
            float s = 0.f;
            for (int k = 0; k < len; ++k) s += tp[c * TPS + e + k];
            unsafeAtomicAdd(&out[(size_t)SRCs[e] * 80 + c], s);
        }
    }
}

extern "C" void kernel_launch(void* const* d_in, const int* in_sizes, int n_in,
                              void* d_out, int out_size, void* d_ws, size_t ws_size,
                              hipStream_t stream) {
    const float* node_attr  = (const float*)d_in[0];
    const int*   edge_index = (const int*)d_in[1];
    const float* edge_attr  = (const float*)d_in[2];
    const float* edge_sh    = (const float*)d_in[3];
    const float* fc_w1      = (const float*)d_in[4];
    const float* fc_b1      = (const float*)d_in[5];
    const float* fc_w2      = (const float*)d_in[6];
    const float* fc_b2      = (const float*)d_in[7];
    int N = in_sizes[0] / 80;
    int E = in_sizes[1] / 2;
    float* out = (float*)d_out;

    int* cnt  = (int*)d_ws;
    int* cur  = cnt + N;
    int* perm = cur + N;
    u16* w2frag = (u16*)(perm + E);              // 294912 u16
    u16* w1t    = w2frag + (size_t)NTILES * 4 * 64 * 8;

    hipMemsetAsync(out, 0, (size_t)N * 80 * 4, stream);
    hipMemsetAsync(cnt, 0, (size_t)N * 4, stream);

    int prep_total = NTILES * 4 * 64 * 8 + 128 * 32;
    prep_w<<<(prep_total + 255) / 256, 256, 0, stream>>>(fc_w2, fc_w1, w2frag, w1t);
    count_k<<<(E + 255) / 256, 256, 0, stream>>>(edge_index, E, cnt);
    scan_k<<<1, 1024, 0, stream>>>(cnt, cur, N);
    scatter_k<<<(E + 255) / 256, 256, 0, stream>>>(edge_index, E, cur, perm);
    tpcl_main<<<(E + E_TILE - 1) / E_TILE, 256, 0, stream>>>(
        node_attr, edge_index, edge_attr, edge_sh, w1t, fc_b1, fc_b2, w2frag, perm, out, N, E);
    finalize_k<<<(N * 80 + 255) / 256, 256, 0, stream>>>(out, cnt, N * 80);
}